// Round 1
// baseline (285.571 us; speedup 1.0000x reference)
//
#include <hip/hip_runtime.h>

#define HH 256
#define WW 384
#define HWSZ (HH*WW)
#define NL 3
#define ANGN 7
#define A2N 49
#define NBATCH 2
#define RANKN 4
#define CN 3
#define RCN (RANKN*CN)

__global__ __launch_bounds__(256) void multilayer_kernel(
    const float* __restrict__ low_rank,   // (N, L, R, C, H, W)
    const float* __restrict__ planes,     // (N, L)
    float* __restrict__ out)              // (N, A2, C, H, W)
{
    // block decomposition: [n][a][pixel-block]
    int b = blockIdx.x;
    int pb = b % (HWSZ / 256);
    int na = b / (HWSZ / 256);
    int a  = na % A2N;
    int n  = na / A2N;

    int tid = pb * 256 + (int)threadIdx.x;
    int y = tid / WW;
    int x = tid % WW;
    float xf = (float)x, yf = (float)y;

    // shifts: shift_x(a) = (-1/W) * (a%7 - 3); shift_y(a) = (-1/H) * (a/7 - 3)
    // pixel-space displacement scale: dx = p * shift_x * 0.5 * (W-1)
    int lidx = a % ANGN - 3;
    int kidx = a / ANGN - 3;
    float sxa = -(float)lidx * (1.0f / WW) * 0.5f * (float)(WW - 1);
    float sya = -(float)kidx * (1.0f / HH) * 0.5f * (float)(HH - 1);

    float acc[RCN];
#pragma unroll
    for (int i = 0; i < RCN; i++) acc[i] = 1.0f;

#pragma unroll
    for (int l = 0; l < NL; l++) {
        float p = planes[n * NL + l];   // uniform per block -> scalar load

        float X = fminf(fmaxf(xf + p * sxa, 0.0f), (float)(WW - 1));
        float Y = fminf(fmaxf(yf + p * sya, 0.0f), (float)(HH - 1));
        float x0f = floorf(X), y0f = floorf(Y);
        int x0 = (int)x0f, y0 = (int)y0f;
        int x1 = min(x0 + 1, WW - 1);
        int y1 = min(y0 + 1, HH - 1);
        float wx = X - x0f, wy = Y - y0f;
        float w00 = (1.0f - wx) * (1.0f - wy);
        float w01 = wx * (1.0f - wy);
        float w10 = (1.0f - wx) * wy;
        float w11 = wx * wy;

        const float* img = low_rank + (size_t)((n * NL + l) * RCN) * HWSZ;
        const float* r0 = img + y0 * WW;
        const float* r1 = img + y1 * WW;

#pragma unroll
        for (int rc = 0; rc < RCN; rc++) {
            float v00 = r0[rc * HWSZ + x0];
            float v01 = r0[rc * HWSZ + x1];
            float v10 = r1[rc * HWSZ + x0];
            float v11 = r1[rc * HWSZ + x1];
            float s = v00 * w00 + v01 * w01 + v10 * w10 + v11 * w11;
            acc[rc] *= s;
        }
    }

    // out[n][a][c][y][x] = mean over r of acc[r*C+c]
    int obase = ((n * A2N + a) * CN) * HWSZ + y * WW + x;
#pragma unroll
    for (int c = 0; c < CN; c++) {
        float s = acc[0 * CN + c] + acc[1 * CN + c] + acc[2 * CN + c] + acc[3 * CN + c];
        out[obase + c * HWSZ] = 0.25f * s;
    }
}

extern "C" void kernel_launch(void* const* d_in, const int* in_sizes, int n_in,
                              void* d_out, int out_size, void* d_ws, size_t ws_size,
                              hipStream_t stream) {
    const float* low_rank = (const float*)d_in[0];
    const float* planes   = (const float*)d_in[1];
    float* out = (float*)d_out;

    int blocks = NBATCH * A2N * (HWSZ / 256);   // 37632
    multilayer_kernel<<<blocks, 256, 0, stream>>>(low_rank, planes, out);
}